// Round 3
// baseline (610.409 us; speedup 1.0000x reference)
//
#include <hip/hip_runtime.h>
#include <math.h>

#define N_NODES 100000
#define C 64
#define EPS 1e-9f
#define SCAN_BLK 1024
#define NBLK ((N_NODES + SCAN_BLK - 1) / SCAN_BLK)   // 98

// ---------------------------------------------------------------------------
// K1: histogram of dst -> cnt[]
// ---------------------------------------------------------------------------
__global__ void hist_kernel(const int* __restrict__ dst, int* __restrict__ cnt, int E) {
    int stride = gridDim.x * blockDim.x;
    for (int i = blockIdx.x * blockDim.x + threadIdx.x; i < E; i += stride)
        atomicAdd(&cnt[dst[i]], 1);
}

// ---------------------------------------------------------------------------
// K2a: per-block exclusive scan of cnt -> off, block totals -> bsum
// ---------------------------------------------------------------------------
__global__ void scan_block_kernel(const int* __restrict__ cnt, int* __restrict__ off,
                                  int* __restrict__ bsum, int n) {
    __shared__ int tmp[SCAN_BLK];
    int tid = threadIdx.x;
    int gid = blockIdx.x * SCAN_BLK + tid;
    int v = (gid < n) ? cnt[gid] : 0;
    tmp[tid] = v;
    __syncthreads();
    for (int d = 1; d < SCAN_BLK; d <<= 1) {
        int t = (tid >= d) ? tmp[tid - d] : 0;
        __syncthreads();
        tmp[tid] += t;
        __syncthreads();
    }
    if (gid < n) off[gid] = tmp[tid] - v;            // exclusive within block
    if (tid == SCAN_BLK - 1) bsum[blockIdx.x] = tmp[tid];
}

// ---------------------------------------------------------------------------
// K2b: exclusive scan of block sums (single block, 128 threads >= NBLK)
// ---------------------------------------------------------------------------
__global__ void scan_bsum_kernel(int* __restrict__ bsum, int nb) {
    __shared__ int tmp[128];
    int tid = threadIdx.x;
    int v = (tid < nb) ? bsum[tid] : 0;
    tmp[tid] = v;
    __syncthreads();
    for (int d = 1; d < 128; d <<= 1) {
        int t = (tid >= d) ? tmp[tid - d] : 0;
        __syncthreads();
        tmp[tid] += t;
        __syncthreads();
    }
    if (tid < nb) bsum[tid] = tmp[tid] - v;          // exclusive
}

// ---------------------------------------------------------------------------
// K2c: add block offsets; seed cursor = off; set off[N] = E
// ---------------------------------------------------------------------------
__global__ void scan_add_kernel(int* __restrict__ off, const int* __restrict__ bsum,
                                int* __restrict__ cursor, int n, int E) {
    int gid = blockIdx.x * SCAN_BLK + threadIdx.x;
    if (gid < n) {
        int v = off[gid] + bsum[blockIdx.x];
        off[gid] = v;
        cursor[gid] = v;            // build kernel bumps this directly
    }
    if (gid == 0) off[n] = E;
}

// ---------------------------------------------------------------------------
// K3: CSR build. pos = cursor[d]++ ; csr[pos] = src
// ---------------------------------------------------------------------------
__global__ void build_kernel(const int* __restrict__ src, const int* __restrict__ dst,
                             int* __restrict__ cursor, int* __restrict__ csr, int E) {
    int stride = gridDim.x * blockDim.x;
    for (int i = blockIdx.x * blockDim.x + threadIdx.x; i < E; i += stride) {
        int d = dst[i];
        int p = atomicAdd(&cursor[d], 1);
        csr[p] = src[i];
    }
}

// ---------------------------------------------------------------------------
// K4: fused per-node. Vectorized gather: lane = (row-group r, chan-block q),
// each lane loads float4 -> one instruction gathers 4 rows (1KB), 4
// independent loads in the body -> 16 rows in flight per wave.
// Then shfl_xor(16,32) folds row-groups; matvec from LDS-transposed weights;
// relu; butterfly L2 norm.
// ---------------------------------------------------------------------------
__global__ void __launch_bounds__(1024)
fused_kernel(const float* __restrict__ x, const int* __restrict__ off,
             const int* __restrict__ csr,
             const float* __restrict__ Wl, const float* __restrict__ bl,
             const float* __restrict__ Wr, float* __restrict__ out) {
    __shared__ float WT_l[C][C + 1];
    __shared__ float WT_r[C][C + 1];

    const int tid = threadIdx.x;
    for (int t = tid; t < C * C; t += blockDim.x) {
        int c = t >> 6;
        int k = t & 63;
        WT_l[k][c] = Wl[t];
        WT_r[k][c] = Wr[t];
    }
    __syncthreads();

    const int wid = tid >> 6;
    const int lane = tid & 63;
    const int r = lane >> 4;          // row-group 0..3
    const int q = lane & 15;          // chan-block 0..15 (channels 4q..4q+3)
    const int wpb = blockDim.x >> 6;  // 16 waves/block
    const float bias = bl[lane];
    const float4* __restrict__ x4 = (const float4*)x;   // row stride = 16 float4

    for (int n = blockIdx.x * wpb + wid; n < N_NODES;
         n += gridDim.x * wpb) {
        const int o0 = off[n];
        const int o1 = off[n + 1];
        const int deg = o1 - o0;

        float4 p0 = make_float4(0.f, 0.f, 0.f, 0.f);
        float4 p1 = p0, p2 = p0, p3 = p0;

        for (int jb = o0 + r; jb < o1; jb += 16) {
            {
                int row = csr[jb];
                float4 v = x4[(size_t)row * 16 + q];
                p0.x += v.x; p0.y += v.y; p0.z += v.z; p0.w += v.w;
            }
            if (jb + 4 < o1) {
                int row = csr[jb + 4];
                float4 v = x4[(size_t)row * 16 + q];
                p1.x += v.x; p1.y += v.y; p1.z += v.z; p1.w += v.w;
            }
            if (jb + 8 < o1) {
                int row = csr[jb + 8];
                float4 v = x4[(size_t)row * 16 + q];
                p2.x += v.x; p2.y += v.y; p2.z += v.z; p2.w += v.w;
            }
            if (jb + 12 < o1) {
                int row = csr[jb + 12];
                float4 v = x4[(size_t)row * 16 + q];
                p3.x += v.x; p3.y += v.y; p3.z += v.z; p3.w += v.w;
            }
        }

        float av[4];
        av[0] = (p0.x + p1.x) + (p2.x + p3.x);
        av[1] = (p0.y + p1.y) + (p2.y + p3.y);
        av[2] = (p0.z + p1.z) + (p2.z + p3.z);
        av[3] = (p0.w + p1.w) + (p2.w + p3.w);
#pragma unroll
        for (int c = 0; c < 4; ++c) {
            av[c] += __shfl_xor(av[c], 16);
            av[c] += __shfl_xor(av[c], 32);
        }
        const float inv = 1.0f / (float)max(deg, 1);
        av[0] *= inv; av[1] *= inv; av[2] *= inv; av[3] *= inv;

        const float xv = x[(size_t)n * C + lane];

        float acc = bias;
#pragma unroll
        for (int k = 0; k < C; ++k) {
            float ak = __shfl(av[k & 3], k >> 2);
            float xk = __shfl(xv, k);
            acc = fmaf(ak, WT_l[k][lane], acc);
            acc = fmaf(xk, WT_r[k][lane], acc);
        }
        acc = fmaxf(acc, 0.0f);

        float sq = acc * acc;
#pragma unroll
        for (int o = 32; o > 0; o >>= 1)
            sq += __shfl_xor(sq, o);

        out[(size_t)n * C + lane] = acc / (sqrtf(sq) + EPS);
    }
}

extern "C" void kernel_launch(void* const* d_in, const int* in_sizes, int n_in,
                              void* d_out, int out_size, void* d_ws, size_t ws_size,
                              hipStream_t stream) {
    const float* x    = (const float*)d_in[0];
    const int*   edge = (const int*)d_in[1];
    const float* Wl   = (const float*)d_in[2];
    const float* bl   = (const float*)d_in[3];
    const float* Wr   = (const float*)d_in[4];
    float*       out  = (float*)d_out;

    const int E = in_sizes[1] / 2;
    const int* src = edge;
    const int* dst = edge + E;

    int* cnt    = (int*)d_ws;                 // [N]
    int* cursor = cnt + N_NODES;              // [N]
    int* off    = cursor + N_NODES;           // [N+1]
    int* bsum   = off + N_NODES + 1;          // [128]
    int* csr    = bsum + 128;                 // [E]

    // zero cnt only (cursor is overwritten by scan_add)
    hipMemsetAsync(cnt, 0, (size_t)N_NODES * sizeof(int), stream);

    hist_kernel<<<2048, 256, 0, stream>>>(dst, cnt, E);
    scan_block_kernel<<<NBLK, SCAN_BLK, 0, stream>>>(cnt, off, bsum, N_NODES);
    scan_bsum_kernel<<<1, 128, 0, stream>>>(bsum, NBLK);
    scan_add_kernel<<<NBLK, SCAN_BLK, 0, stream>>>(off, bsum, cursor, N_NODES, E);
    build_kernel<<<2048, 256, 0, stream>>>(src, dst, cursor, csr, E);
    fused_kernel<<<1024, 1024, 0, stream>>>(x, off, csr, Wl, bl, Wr, out);
}

// Round 4
// 520.280 us; speedup vs baseline: 1.1732x; 1.1732x over previous
//
#include <hip/hip_runtime.h>
#include <math.h>

#define N_NODES 100000
#define C 64
#define EPS 1e-9f
#define SCAN_BLK 1024
#define NBLK ((N_NODES + SCAN_BLK - 1) / SCAN_BLK)   // 98
#define NXCD 8
#define GCHUNKS 512          // gather blocks per slice
#define NPC ((N_NODES + GCHUNKS - 1) / GCHUNKS)      // 196 nodes/chunk

// ---------------------------------------------------------------------------
// K1: histogram of dst -> cnt[]
// ---------------------------------------------------------------------------
__global__ void hist_kernel(const int* __restrict__ dst, int* __restrict__ cnt, int E) {
    int stride = gridDim.x * blockDim.x;
    for (int i = blockIdx.x * blockDim.x + threadIdx.x; i < E; i += stride)
        atomicAdd(&cnt[dst[i]], 1);
}

// ---------------------------------------------------------------------------
// K2a: per-block exclusive scan of cnt -> off, block totals -> bsum
// ---------------------------------------------------------------------------
__global__ void scan_block_kernel(const int* __restrict__ cnt, int* __restrict__ off,
                                  int* __restrict__ bsum, int n) {
    __shared__ int tmp[SCAN_BLK];
    int tid = threadIdx.x;
    int gid = blockIdx.x * SCAN_BLK + tid;
    int v = (gid < n) ? cnt[gid] : 0;
    tmp[tid] = v;
    __syncthreads();
    for (int d = 1; d < SCAN_BLK; d <<= 1) {
        int t = (tid >= d) ? tmp[tid - d] : 0;
        __syncthreads();
        tmp[tid] += t;
        __syncthreads();
    }
    if (gid < n) off[gid] = tmp[tid] - v;
    if (tid == SCAN_BLK - 1) bsum[blockIdx.x] = tmp[tid];
}

// ---------------------------------------------------------------------------
// K2b: exclusive scan of block sums (single block)
// ---------------------------------------------------------------------------
__global__ void scan_bsum_kernel(int* __restrict__ bsum, int nb) {
    __shared__ int tmp[128];
    int tid = threadIdx.x;
    int v = (tid < nb) ? bsum[tid] : 0;
    tmp[tid] = v;
    __syncthreads();
    for (int d = 1; d < 128; d <<= 1) {
        int t = (tid >= d) ? tmp[tid - d] : 0;
        __syncthreads();
        tmp[tid] += t;
        __syncthreads();
    }
    if (tid < nb) bsum[tid] = tmp[tid] - v;
}

// ---------------------------------------------------------------------------
// K2c: add block offsets; seed cursor = off; set off[N] = E
// ---------------------------------------------------------------------------
__global__ void scan_add_kernel(int* __restrict__ off, const int* __restrict__ bsum,
                                int* __restrict__ cursor, int n, int E) {
    int gid = blockIdx.x * SCAN_BLK + threadIdx.x;
    if (gid < n) {
        int v = off[gid] + bsum[blockIdx.x];
        off[gid] = v;
        cursor[gid] = v;
    }
    if (gid == 0) off[n] = E;
}

// ---------------------------------------------------------------------------
// K3: CSR build, dst-range-sliced across XCDs. Slice s (= blockIdx&7, lands
// on XCD s under round-robin dispatch) handles dst in [s*12500, (s+1)*12500):
// its cursor atomics + scattered csr writes stay in ONE L2 (~800KB region),
// written back once instead of line-ping-ponging across 8 L2s.
// Cost: edge list read 8x (L3-served).
// ---------------------------------------------------------------------------
__global__ void build_kernel(const int* __restrict__ src, const int* __restrict__ dst,
                             int* __restrict__ cursor, int* __restrict__ csr, int E) {
    const int s  = blockIdx.x & (NXCD - 1);
    const int lo = s * (N_NODES / NXCD);
    const int hi = lo + (N_NODES / NXCD);
    const int nchunk = gridDim.x >> 3;
    const int chunk  = blockIdx.x >> 3;
    const int stride = nchunk * blockDim.x;
    for (int i = chunk * blockDim.x + threadIdx.x; i < E; i += stride) {
        int d = dst[i];
        if (d >= lo && d < hi) {
            int p = atomicAdd(&cursor[d], 1);
            csr[p] = src[i];
        }
    }
}

// ---------------------------------------------------------------------------
// K4: channel-sliced gather-mean. Slice s = blockIdx&7 -> XCD s; this XCD
// only ever touches x[:, 8s:8s+8] = 3.2MB -> L2-RESIDENT. Lane = (row-group
// r=lane>>3, channel c=lane&7). Per instruction: 8 rows x 32B contiguous.
// Mean written to agg (= d_out scratch) with nontemporal stores.
// ---------------------------------------------------------------------------
__global__ void __launch_bounds__(256)
slice_gather_kernel(const float* __restrict__ x, const int* __restrict__ off,
                    const int* __restrict__ csr, float* __restrict__ agg) {
    const int s     = blockIdx.x & (NXCD - 1);
    const int chunk = blockIdx.x >> 3;
    const int n0 = chunk * NPC;
    const int n1 = min(n0 + NPC, N_NODES);
    const int wid  = threadIdx.x >> 6;
    const int lane = threadIdx.x & 63;
    const int r = lane >> 3;                  // 0..7 row group
    const int c = lane & 7;                   // channel within slice
    const float* __restrict__ xs = x + s * 8 + c;

    for (int n = n0 + wid; n < n1; n += 4) {
        const int o0 = off[n];
        const int o1 = off[n + 1];

        float sum = 0.0f, sum2 = 0.0f;
        int j = o0 + r;
        for (; j + 8 < o1; j += 16) {
            int row0 = csr[j];
            int row1 = csr[j + 8];
            sum  += xs[(size_t)row0 * C];
            sum2 += xs[(size_t)row1 * C];
        }
        if (j < o1) sum += xs[(size_t)csr[j] * C];
        sum += sum2;

        sum += __shfl_xor(sum, 8);
        sum += __shfl_xor(sum, 16);
        sum += __shfl_xor(sum, 32);

        if (r == 0) {
            int deg = o1 - o0;
            float m = sum / (float)max(deg, 1);
            __builtin_nontemporal_store(m, &agg[(size_t)n * C + s * 8 + c]);
        }
    }
}

// ---------------------------------------------------------------------------
// K5: transform in place on io (= agg = out): lin_l(agg)+b+lin_r(x) -> relu
// -> L2 norm. One wave per node; lane = out channel. Weights transposed in
// LDS (+1 pad); row broadcasts via __shfl. Each thread reads io before
// writing the same element -> alias-safe.
// ---------------------------------------------------------------------------
__global__ void __launch_bounds__(256)
transform_kernel(const float* __restrict__ x, float* io,
                 const float* __restrict__ Wl, const float* __restrict__ bl,
                 const float* __restrict__ Wr) {
    __shared__ float WT_l[C][C + 1];
    __shared__ float WT_r[C][C + 1];

    const int tid = threadIdx.x;
    for (int t = tid; t < C * C; t += blockDim.x) {
        int cc = t >> 6;
        int k  = t & 63;
        WT_l[k][cc] = Wl[t];
        WT_r[k][cc] = Wr[t];
    }
    __syncthreads();

    const int wid  = tid >> 6;
    const int lane = tid & 63;
    const int wpb  = blockDim.x >> 6;     // 4
    const float bias = bl[lane];

    for (int n = blockIdx.x * wpb + wid; n < N_NODES; n += gridDim.x * wpb) {
        float a  = io[(size_t)n * C + lane];
        float xv = x[(size_t)n * C + lane];

        float acc = bias;
#pragma unroll
        for (int k = 0; k < C; ++k) {
            float ak = __shfl(a, k);
            float xk = __shfl(xv, k);
            acc = fmaf(ak, WT_l[k][lane], acc);
            acc = fmaf(xk, WT_r[k][lane], acc);
        }
        acc = fmaxf(acc, 0.0f);

        float sq = acc * acc;
#pragma unroll
        for (int o = 32; o > 0; o >>= 1)
            sq += __shfl_xor(sq, o);

        __builtin_nontemporal_store(acc / (sqrtf(sq) + EPS),
                                    &io[(size_t)n * C + lane]);
    }
}

extern "C" void kernel_launch(void* const* d_in, const int* in_sizes, int n_in,
                              void* d_out, int out_size, void* d_ws, size_t ws_size,
                              hipStream_t stream) {
    const float* x    = (const float*)d_in[0];
    const int*   edge = (const int*)d_in[1];
    const float* Wl   = (const float*)d_in[2];
    const float* bl   = (const float*)d_in[3];
    const float* Wr   = (const float*)d_in[4];
    float*       out  = (float*)d_out;

    const int E = in_sizes[1] / 2;
    const int* src = edge;
    const int* dst = edge + E;

    int* cnt    = (int*)d_ws;                 // [N]
    int* cursor = cnt + N_NODES;              // [N]
    int* off    = cursor + N_NODES;           // [N+1]
    int* bsum   = off + N_NODES + 1;          // [128]
    int* csr    = bsum + 128;                 // [E]
    float* agg  = out;                        // reuse d_out as agg scratch

    hipMemsetAsync(cnt, 0, (size_t)N_NODES * sizeof(int), stream);

    hist_kernel<<<1024, 256, 0, stream>>>(dst, cnt, E);
    scan_block_kernel<<<NBLK, SCAN_BLK, 0, stream>>>(cnt, off, bsum, N_NODES);
    scan_bsum_kernel<<<1, 128, 0, stream>>>(bsum, NBLK);
    scan_add_kernel<<<NBLK, SCAN_BLK, 0, stream>>>(off, bsum, cursor, N_NODES, E);
    build_kernel<<<NXCD * 256, 256, 0, stream>>>(src, dst, cursor, csr, E);
    slice_gather_kernel<<<NXCD * GCHUNKS, 256, 0, stream>>>(x, off, csr, agg);
    transform_kernel<<<2048, 256, 0, stream>>>(x, agg, Wl, bl, Wr);
}

// Round 5
// 357.985 us; speedup vs baseline: 1.7051x; 1.4534x over previous
//
#include <hip/hip_runtime.h>
#include <math.h>

#define N_NODES 100000
#define C 64
#define EPS 1e-9f
#define SCAN_BLK 1024
#define NXCD 8
#define NG 4                                   // src-range buckets
#define RNG (N_NODES / NG)                     // 25000 rows per range
#define KEYS (N_NODES * NG)                    // 400000 (dst,g) keys
#define NBLK1 ((N_NODES + SCAN_BLK - 1) / SCAN_BLK)   // 98
#define NBLK2 ((KEYS + SCAN_BLK - 1) / SCAN_BLK)      // 391
#define GCH 512
#define NPC ((N_NODES + GCH - 1) / GCH)        // 196 nodes/chunk

typedef __attribute__((ext_vector_type(8))) short bf16x8;
typedef __attribute__((ext_vector_type(4))) float f32x4;

__device__ __forceinline__ unsigned short f2bf(float f) {
    union { float f; unsigned int u; } v; v.f = f;
    unsigned int u = v.u;
    return (unsigned short)((u + 0x7FFFu + ((u >> 16) & 1u)) >> 16);
}

// ===========================================================================
// Shared scan kernels (generic n)
// ===========================================================================
__global__ void scan_block_kernel(const int* __restrict__ cnt, int* __restrict__ off,
                                  int* __restrict__ bsum, int n) {
    __shared__ int tmp[SCAN_BLK];
    int tid = threadIdx.x;
    int gid = blockIdx.x * SCAN_BLK + tid;
    int v = (gid < n) ? cnt[gid] : 0;
    tmp[tid] = v;
    __syncthreads();
    for (int d = 1; d < SCAN_BLK; d <<= 1) {
        int t = (tid >= d) ? tmp[tid - d] : 0;
        __syncthreads();
        tmp[tid] += t;
        __syncthreads();
    }
    if (gid < n) off[gid] = tmp[tid] - v;
    if (tid == SCAN_BLK - 1) bsum[blockIdx.x] = tmp[tid];
}

__global__ void scan_bsum_kernel(int* __restrict__ bsum, int nb) {
    __shared__ int tmp[512];
    int tid = threadIdx.x;
    int v = (tid < nb) ? bsum[tid] : 0;
    tmp[tid] = v;
    __syncthreads();
    for (int d = 1; d < 512; d <<= 1) {
        int t = (tid >= d) ? tmp[tid - d] : 0;
        __syncthreads();
        tmp[tid] += t;
        __syncthreads();
    }
    if (tid < nb) bsum[tid] = tmp[tid] - v;
}

__global__ void scan_add_kernel(int* __restrict__ off, const int* __restrict__ bsum,
                                int* __restrict__ cursor, int n, int E) {
    int gid = blockIdx.x * SCAN_BLK + threadIdx.x;
    if (gid < n) {
        int v = off[gid] + bsum[blockIdx.x];
        off[gid] = v;
        cursor[gid] = v;
    }
    if (gid == 0) off[n] = E;
}

// ===========================================================================
// NEW PATH: (dst,g)-keyed CSR + XCD-local gather + MFMA transform
// ===========================================================================
// hist over key = dst*4 + (src/25000), dst-range-sliced so atomics are
// XCD-local (cnt2 region per slice = 200KB).
__global__ void hist2_kernel(const int* __restrict__ src, const int* __restrict__ dst,
                             int* __restrict__ cnt2, int E) {
    const int s  = blockIdx.x & (NXCD - 1);
    const int lo = s * (N_NODES / NXCD);
    const int hi = lo + (N_NODES / NXCD);
    const int stride = (gridDim.x >> 3) * blockDim.x;
    for (int i = (blockIdx.x >> 3) * blockDim.x + threadIdx.x; i < E; i += stride) {
        int d = dst[i];
        if (d >= lo && d < hi) {
            int g = src[i] / RNG;
            atomicAdd(&cnt2[d * NG + g], 1);
        }
    }
}

__global__ void build2_kernel(const int* __restrict__ src, const int* __restrict__ dst,
                              int* __restrict__ cursor2, int* __restrict__ csr, int E) {
    const int s  = blockIdx.x & (NXCD - 1);
    const int lo = s * (N_NODES / NXCD);
    const int hi = lo + (N_NODES / NXCD);
    const int stride = (gridDim.x >> 3) * blockDim.x;
    for (int i = (blockIdx.x >> 3) * blockDim.x + threadIdx.x; i < E; i += stride) {
        int d = dst[i];
        if (d >= lo && d < hi) {
            int sv = src[i];
            int g = sv / RNG;
            int p = atomicAdd(&cursor2[d * NG + g], 1);
            csr[p] = sv;
        }
    }
}

// Slice (g,h) on XCD 2g+h: gathers only x[g*25000:(g+1)*25000, 32h:32h+32]
// = 25000 rows x 128B (one full cache line) = 3.2MB -> L2-RESIDENT.
// Writes disjoint f32 partial sums (no atomics).
__global__ void __launch_bounds__(256)
gatherP_kernel(const float* __restrict__ x, const int* __restrict__ off2,
               const int* __restrict__ csr,
               float* __restrict__ P0, float* __restrict__ P1,
               float* __restrict__ P2, float* __restrict__ P3) {
    const int sid = blockIdx.x & (NXCD - 1);
    const int g = sid >> 1;
    const int h = sid & 1;
    float* __restrict__ P = (g == 0) ? P0 : (g == 1) ? P1 : (g == 2) ? P2 : P3;
    const int chunk = blockIdx.x >> 3;
    const int n0 = chunk * NPC;
    const int n1 = min(n0 + NPC, N_NODES);
    const int wid  = threadIdx.x >> 6;
    const int lane = threadIdx.x & 63;
    const int r = lane >> 5;                  // entry parity 0/1
    const int c = lane & 31;                  // channel within half
    const float* __restrict__ xs = x + h * 32 + c;

    for (int n = n0 + wid; n < n1; n += 4) {
        const int base = off2[4 * n + g];
        const int end  = off2[4 * n + g + 1];
        float sum = 0.0f;
        for (int j = base + r; j < end; j += 2) {
            int row = csr[j];
            sum += xs[(size_t)row * C];
        }
        sum += __shfl_xor(sum, 32);
        if (r == 0)
            __builtin_nontemporal_store(sum, &P[(size_t)n * C + h * 32 + c]);
    }
}

// GEMM [agg|x](100K x 128) @ [Wl;Wr]^T via mfma_f32_16x16x32_bf16.
// Per wave: 16-node tile, 4 col-blocks x 4 k-steps = 16 MFMAs.
// A row = lane&15, k = ks*32 + (lane>>4)*8 + j ; C/D: col=lane&15,
// row=(lane>>4)*4+reg. Fused bias+relu+L2norm epilogue.
__global__ void __launch_bounds__(256)
transform_mfma_kernel(const float* __restrict__ x, const int* __restrict__ off2,
                      const float* __restrict__ P0, const float* __restrict__ P1,
                      const float* __restrict__ P2, const float* __restrict__ P3,
                      const float* __restrict__ Wl, const float* __restrict__ bl,
                      const float* __restrict__ Wr, float* __restrict__ out) {
    const int lane = threadIdx.x & 63;
    const int wid  = threadIdx.x >> 6;
    const int col  = lane & 15;
    const int lg   = lane >> 4;

    bf16x8 Bf[4][4];
    float bias[4];
#pragma unroll
    for (int cb = 0; cb < 4; ++cb) {
        const int cc = cb * 16 + col;
        bias[cb] = bl[cc];
#pragma unroll
        for (int ks = 0; ks < 4; ++ks) {
            const int kk0 = ks * 32 + lg * 8;
            const float* W = (kk0 < 64) ? (Wl + (size_t)cc * 64 + kk0)
                                        : (Wr + (size_t)cc * 64 + (kk0 - 64));
            float4 w0 = *(const float4*)W;
            float4 w1 = *(const float4*)(W + 4);
            bf16x8 b;
            b[0]=(short)f2bf(w0.x); b[1]=(short)f2bf(w0.y);
            b[2]=(short)f2bf(w0.z); b[3]=(short)f2bf(w0.w);
            b[4]=(short)f2bf(w1.x); b[5]=(short)f2bf(w1.y);
            b[6]=(short)f2bf(w1.z); b[7]=(short)f2bf(w1.w);
            Bf[cb][ks] = b;
        }
    }

    const int ntiles = N_NODES / 16;          // 6250, exact
    for (int t = blockIdx.x * 4 + wid; t < ntiles; t += gridDim.x * 4) {
        const int n0 = t * 16;
        const int arow = n0 + col;
        const int d0 = off2[4 * arow];
        const int d1 = off2[4 * arow + 4];
        const int deg = d1 - d0;
        const float inv = 1.0f / (float)(deg > 1 ? deg : 1);

        f32x4 acc[4];
#pragma unroll
        for (int cb = 0; cb < 4; ++cb) acc[cb] = f32x4{0.f, 0.f, 0.f, 0.f};

#pragma unroll
        for (int ks = 0; ks < 4; ++ks) {
            const int kk0 = ks * 32 + lg * 8;
            bf16x8 a;
            if (kk0 < 64) {
                const float4* p0 = (const float4*)(P0 + (size_t)arow * C + kk0);
                const float4* p1 = (const float4*)(P1 + (size_t)arow * C + kk0);
                const float4* p2 = (const float4*)(P2 + (size_t)arow * C + kk0);
                const float4* p3 = (const float4*)(P3 + (size_t)arow * C + kk0);
                float4 a0 = p0[0], b0 = p1[0], c0 = p2[0], e0 = p3[0];
                float4 a1 = p0[1], b1 = p1[1], c1 = p2[1], e1 = p3[1];
                float s0x = ((a0.x + b0.x) + (c0.x + e0.x)) * inv;
                float s0y = ((a0.y + b0.y) + (c0.y + e0.y)) * inv;
                float s0z = ((a0.z + b0.z) + (c0.z + e0.z)) * inv;
                float s0w = ((a0.w + b0.w) + (c0.w + e0.w)) * inv;
                float s1x = ((a1.x + b1.x) + (c1.x + e1.x)) * inv;
                float s1y = ((a1.y + b1.y) + (c1.y + e1.y)) * inv;
                float s1z = ((a1.z + b1.z) + (c1.z + e1.z)) * inv;
                float s1w = ((a1.w + b1.w) + (c1.w + e1.w)) * inv;
                a[0]=(short)f2bf(s0x); a[1]=(short)f2bf(s0y);
                a[2]=(short)f2bf(s0z); a[3]=(short)f2bf(s0w);
                a[4]=(short)f2bf(s1x); a[5]=(short)f2bf(s1y);
                a[6]=(short)f2bf(s1z); a[7]=(short)f2bf(s1w);
            } else {
                const float4* xp = (const float4*)(x + (size_t)arow * C + (kk0 - 64));
                float4 v0 = xp[0], v1 = xp[1];
                a[0]=(short)f2bf(v0.x); a[1]=(short)f2bf(v0.y);
                a[2]=(short)f2bf(v0.z); a[3]=(short)f2bf(v0.w);
                a[4]=(short)f2bf(v1.x); a[5]=(short)f2bf(v1.y);
                a[6]=(short)f2bf(v1.z); a[7]=(short)f2bf(v1.w);
            }
#pragma unroll
            for (int cb = 0; cb < 4; ++cb)
                acc[cb] = __builtin_amdgcn_mfma_f32_16x16x32_bf16(a, Bf[cb][ks], acc[cb], 0, 0, 0);
        }

#pragma unroll
        for (int j = 0; j < 4; ++j) {
            float v0 = fmaxf(acc[0][j] + bias[0], 0.0f);
            float v1 = fmaxf(acc[1][j] + bias[1], 0.0f);
            float v2 = fmaxf(acc[2][j] + bias[2], 0.0f);
            float v3 = fmaxf(acc[3][j] + bias[3], 0.0f);
            float s = (v0 * v0 + v1 * v1) + (v2 * v2 + v3 * v3);
            s += __shfl_xor(s, 1);
            s += __shfl_xor(s, 2);
            s += __shfl_xor(s, 4);
            s += __shfl_xor(s, 8);
            float rr = 1.0f / (sqrtf(s) + EPS);
            const int n = n0 + lg * 4 + j;
            float* o = out + (size_t)n * C + col;
            o[0]  = v0 * rr;
            o[16] = v1 * rr;
            o[32] = v2 * rr;
            o[48] = v3 * rr;
        }
    }
}

// ===========================================================================
// FALLBACK PATH (round-4 pipeline) — used only if ws_size is too small
// ===========================================================================
__global__ void hist_kernel(const int* __restrict__ dst, int* __restrict__ cnt, int E) {
    int stride = gridDim.x * blockDim.x;
    for (int i = blockIdx.x * blockDim.x + threadIdx.x; i < E; i += stride)
        atomicAdd(&cnt[dst[i]], 1);
}

__global__ void build_kernel(const int* __restrict__ src, const int* __restrict__ dst,
                             int* __restrict__ cursor, int* __restrict__ csr, int E) {
    const int s  = blockIdx.x & (NXCD - 1);
    const int lo = s * (N_NODES / NXCD);
    const int hi = lo + (N_NODES / NXCD);
    const int stride = (gridDim.x >> 3) * blockDim.x;
    for (int i = (blockIdx.x >> 3) * blockDim.x + threadIdx.x; i < E; i += stride) {
        int d = dst[i];
        if (d >= lo && d < hi) {
            int p = atomicAdd(&cursor[d], 1);
            csr[p] = src[i];
        }
    }
}

__global__ void __launch_bounds__(256)
slice_gather_kernel(const float* __restrict__ x, const int* __restrict__ off,
                    const int* __restrict__ csr, float* __restrict__ agg) {
    const int s     = blockIdx.x & (NXCD - 1);
    const int chunk = blockIdx.x >> 3;
    const int n0 = chunk * NPC;
    const int n1 = min(n0 + NPC, N_NODES);
    const int wid  = threadIdx.x >> 6;
    const int lane = threadIdx.x & 63;
    const int r = lane >> 3;
    const int c = lane & 7;
    const float* __restrict__ xs = x + s * 8 + c;

    for (int n = n0 + wid; n < n1; n += 4) {
        const int o0 = off[n];
        const int o1 = off[n + 1];
        float sum = 0.0f, sum2 = 0.0f;
        int j = o0 + r;
        for (; j + 8 < o1; j += 16) {
            sum  += xs[(size_t)csr[j] * C];
            sum2 += xs[(size_t)csr[j + 8] * C];
        }
        if (j < o1) sum += xs[(size_t)csr[j] * C];
        sum += sum2;
        sum += __shfl_xor(sum, 8);
        sum += __shfl_xor(sum, 16);
        sum += __shfl_xor(sum, 32);
        if (r == 0) {
            int deg = o1 - o0;
            float m = sum / (float)max(deg, 1);
            __builtin_nontemporal_store(m, &agg[(size_t)n * C + s * 8 + c]);
        }
    }
}

__global__ void __launch_bounds__(256)
transform_kernel(const float* __restrict__ x, float* io,
                 const float* __restrict__ Wl, const float* __restrict__ bl,
                 const float* __restrict__ Wr) {
    __shared__ float WT_l[C][C + 1];
    __shared__ float WT_r[C][C + 1];
    const int tid = threadIdx.x;
    for (int t = tid; t < C * C; t += blockDim.x) {
        int cc = t >> 6;
        int k  = t & 63;
        WT_l[k][cc] = Wl[t];
        WT_r[k][cc] = Wr[t];
    }
    __syncthreads();
    const int wid  = tid >> 6;
    const int lane = tid & 63;
    const int wpb  = blockDim.x >> 6;
    const float bias = bl[lane];
    for (int n = blockIdx.x * wpb + wid; n < N_NODES; n += gridDim.x * wpb) {
        float a  = io[(size_t)n * C + lane];
        float xv = x[(size_t)n * C + lane];
        float acc = bias;
#pragma unroll
        for (int k = 0; k < C; ++k) {
            acc = fmaf(__shfl(a, k), WT_l[k][lane], acc);
            acc = fmaf(__shfl(xv, k), WT_r[k][lane], acc);
        }
        acc = fmaxf(acc, 0.0f);
        float sq = acc * acc;
#pragma unroll
        for (int o = 32; o > 0; o >>= 1)
            sq += __shfl_xor(sq, o);
        __builtin_nontemporal_store(acc / (sqrtf(sq) + EPS), &io[(size_t)n * C + lane]);
    }
}

// ===========================================================================
extern "C" void kernel_launch(void* const* d_in, const int* in_sizes, int n_in,
                              void* d_out, int out_size, void* d_ws, size_t ws_size,
                              hipStream_t stream) {
    const float* x    = (const float*)d_in[0];
    const int*   edge = (const int*)d_in[1];
    const float* Wl   = (const float*)d_in[2];
    const float* bl   = (const float*)d_in[3];
    const float* Wr   = (const float*)d_in[4];

    const int E = in_sizes[1] / 2;
    const int* src = edge;
    const int* dst = edge + E;
    const int Epad = (E + 3) & ~3;

    const size_t nc = (size_t)N_NODES * C;
    size_t needInts  = 3ull * KEYS + 4 + 512 + Epad;
    size_t needBytes = needInts * 4 + 3ull * nc * 4;

    if (ws_size >= needBytes) {
        // -------- new path --------
        int* cnt2    = (int*)d_ws;
        int* cursor2 = cnt2 + KEYS;
        int* off2    = cursor2 + KEYS;          // KEYS+4 ints reserved
        int* bsum    = off2 + KEYS + 4;         // 512 ints
        int* csr     = bsum + 512;              // Epad ints
        float* P0    = (float*)(csr + Epad);
        float* P1    = P0 + nc;
        float* P2    = P1 + nc;
        float* P3    = (float*)d_out;           // d_out as 4th partial buffer

        hipMemsetAsync(cnt2, 0, (size_t)KEYS * sizeof(int), stream);
        hist2_kernel<<<NXCD * 256, 256, 0, stream>>>(src, dst, cnt2, E);
        scan_block_kernel<<<NBLK2, SCAN_BLK, 0, stream>>>(cnt2, off2, bsum, KEYS);
        scan_bsum_kernel<<<1, 512, 0, stream>>>(bsum, NBLK2);
        scan_add_kernel<<<NBLK2, SCAN_BLK, 0, stream>>>(off2, bsum, cursor2, KEYS, E);
        build2_kernel<<<NXCD * 256, 256, 0, stream>>>(src, dst, cursor2, csr, E);
        gatherP_kernel<<<NXCD * GCH, 256, 0, stream>>>(x, off2, csr, P0, P1, P2, P3);
        transform_mfma_kernel<<<1024, 256, 0, stream>>>(x, off2, P0, P1, P2, P3,
                                                        Wl, bl, Wr, (float*)d_out);
    } else {
        // -------- round-4 fallback --------
        int* cnt    = (int*)d_ws;
        int* cursor = cnt + N_NODES;
        int* off    = cursor + N_NODES;         // N+1 (+pad)
        int* bsum   = off + N_NODES + 4;
        int* csr    = bsum + 512;
        float* agg  = (float*)d_out;

        hipMemsetAsync(cnt, 0, (size_t)N_NODES * sizeof(int), stream);
        hist_kernel<<<1024, 256, 0, stream>>>(dst, cnt, E);
        scan_block_kernel<<<NBLK1, SCAN_BLK, 0, stream>>>(cnt, off, bsum, N_NODES);
        scan_bsum_kernel<<<1, 512, 0, stream>>>(bsum, NBLK1);
        scan_add_kernel<<<NBLK1, SCAN_BLK, 0, stream>>>(off, bsum, cursor, N_NODES, E);
        build_kernel<<<NXCD * 256, 256, 0, stream>>>(src, dst, cursor, csr, E);
        slice_gather_kernel<<<NXCD * GCH, 256, 0, stream>>>(x, off, csr, agg);
        transform_kernel<<<2048, 256, 0, stream>>>(x, agg, Wl, bl, Wr);
    }
}

// Round 6
// 299.821 us; speedup vs baseline: 2.0359x; 1.1940x over previous
//
#include <hip/hip_runtime.h>
#include <math.h>

#define N_NODES 100000
#define C 64
#define EPS 1e-9f
#define SCAN_BLK 1024
#define NXCD 8
#define NG 4
#define RNG (N_NODES / NG)            // 25000 src rows per g-bucket
#define SLICE_N (N_NODES / NXCD)      // 12500 dst rows per slice
#define KEYS (N_NODES * NG)           // 400000 (dst,g) keys
#define NBLK2 ((KEYS + SCAN_BLK - 1) / SCAN_BLK)   // 391
#define GCH 500
#define NPC (N_NODES / GCH)           // 200 nodes/chunk (multiple of 8)

typedef __attribute__((ext_vector_type(8))) short bf16x8;
typedef __attribute__((ext_vector_type(4))) float f32x4;
typedef unsigned short u16;

__device__ __forceinline__ unsigned short f2bf(float f) {
    union { float f; unsigned int u; } v; v.f = f;
    unsigned int u = v.u;
    return (unsigned short)((u + 0x7FFFu + ((u >> 16) & 1u)) >> 16);
}

// ===========================================================================
// Scan kernels (generic n)
// ===========================================================================
__global__ void scan_block_kernel(const int* __restrict__ cnt, int* __restrict__ off,
                                  int* __restrict__ bsum, int n) {
    __shared__ int tmp[SCAN_BLK];
    int tid = threadIdx.x;
    int gid = blockIdx.x * SCAN_BLK + tid;
    int v = (gid < n) ? cnt[gid] : 0;
    tmp[tid] = v;
    __syncthreads();
    for (int d = 1; d < SCAN_BLK; d <<= 1) {
        int t = (tid >= d) ? tmp[tid - d] : 0;
        __syncthreads();
        tmp[tid] += t;
        __syncthreads();
    }
    if (gid < n) off[gid] = tmp[tid] - v;
    if (tid == SCAN_BLK - 1) bsum[blockIdx.x] = tmp[tid];
}

__global__ void scan_bsum_kernel(int* __restrict__ bsum, int nb) {
    __shared__ int tmp[512];
    int tid = threadIdx.x;
    int v = (tid < nb) ? bsum[tid] : 0;
    tmp[tid] = v;
    __syncthreads();
    for (int d = 1; d < 512; d <<= 1) {
        int t = (tid >= d) ? tmp[tid - d] : 0;
        __syncthreads();
        tmp[tid] += t;
        __syncthreads();
    }
    if (tid < nb) bsum[tid] = tmp[tid] - v;
}

__global__ void scan_add_kernel(int* __restrict__ off, const int* __restrict__ bsum,
                                int* __restrict__ cursor, int n, int E) {
    int gid = blockIdx.x * SCAN_BLK + threadIdx.x;
    if (gid < n) {
        int v = off[gid] + bsum[blockIdx.x];
        off[gid] = v;
        cursor[gid] = v;
    }
    if (gid == 0) off[n] = E;
}

// ===========================================================================
// K0: partition edges into 8 dst-range buckets. Per block: LDS count ->
// reserve global range -> place. Writes per-slice (key16, src) arrays so
// hist/build stream ~1.3MB each instead of re-reading 102MB edge list 8x.
// key16 = (d - s*12500)*4 + g  (< 50000, fits u16); cnt2 idx = s*50000+key16.
// ===========================================================================
__global__ void __launch_bounds__(256)
partition_kernel(const int* __restrict__ src, const int* __restrict__ dst,
                 int* __restrict__ bcur, u16* __restrict__ bkey16,
                 int* __restrict__ bsrc, int E, int bcap) {
    __shared__ int lcnt[NXCD];
    __shared__ int lbase[NXCD];
    const int tid = threadIdx.x;
    const int per = (E + gridDim.x - 1) / gridDim.x;
    const int i0 = blockIdx.x * per;
    const int i1 = min(i0 + per, E);

    if (tid < NXCD) lcnt[tid] = 0;
    __syncthreads();
    for (int i = i0 + tid; i < i1; i += 256)
        atomicAdd(&lcnt[dst[i] / SLICE_N], 1);
    __syncthreads();
    if (tid < NXCD) {
        lbase[tid] = atomicAdd(&bcur[tid], lcnt[tid]);
        lcnt[tid] = 0;
    }
    __syncthreads();
    for (int i = i0 + tid; i < i1; i += 256) {
        int d  = dst[i];
        int sv = src[i];
        int s  = d / SLICE_N;
        int p  = lbase[s] + atomicAdd(&lcnt[s], 1);
        size_t pos = (size_t)s * bcap + p;
        bkey16[pos] = (u16)((d - s * SLICE_N) * NG + sv / RNG);
        bsrc[pos] = sv;
    }
}

// hist over bucketed keys; slice s atomics stay in 200KB XCD-local region.
__global__ void hist2p_kernel(const int* __restrict__ bcur,
                              const u16* __restrict__ bkey16,
                              int* __restrict__ cnt2, int bcap) {
    const int s = blockIdx.x & (NXCD - 1);
    const int bn = bcur[s];
    const u16* __restrict__ k = bkey16 + (size_t)s * bcap;
    int* __restrict__ c2 = cnt2 + s * (SLICE_N * NG);
    const int stride = (gridDim.x >> 3) * blockDim.x;
    for (int i = (blockIdx.x >> 3) * blockDim.x + threadIdx.x; i < bn; i += stride)
        atomicAdd(&c2[k[i]], 1);
}

__global__ void build2p_kernel(const int* __restrict__ bcur,
                               const u16* __restrict__ bkey16,
                               const int* __restrict__ bsrc,
                               int* __restrict__ cursor2, int* __restrict__ csr,
                               int bcap) {
    const int s = blockIdx.x & (NXCD - 1);
    const int bn = bcur[s];
    const u16* __restrict__ k  = bkey16 + (size_t)s * bcap;
    const int* __restrict__ sv = bsrc + (size_t)s * bcap;
    int* __restrict__ cur = cursor2 + s * (SLICE_N * NG);
    const int stride = (gridDim.x >> 3) * blockDim.x;
    for (int i = (blockIdx.x >> 3) * blockDim.x + threadIdx.x; i < bn; i += stride) {
        int p = atomicAdd(&cur[k[i]], 1);
        csr[p] = sv[i];
    }
}

// ===========================================================================
// Tier-B (round-5) hist/build: direct 8x edge-list streaming
// ===========================================================================
__global__ void hist2_kernel(const int* __restrict__ src, const int* __restrict__ dst,
                             int* __restrict__ cnt2, int E) {
    const int s  = blockIdx.x & (NXCD - 1);
    const int lo = s * SLICE_N;
    const int hi = lo + SLICE_N;
    const int stride = (gridDim.x >> 3) * blockDim.x;
    for (int i = (blockIdx.x >> 3) * blockDim.x + threadIdx.x; i < E; i += stride) {
        int d = dst[i];
        if (d >= lo && d < hi) {
            int g = src[i] / RNG;
            atomicAdd(&cnt2[d * NG + g], 1);
        }
    }
}

__global__ void build2_kernel(const int* __restrict__ src, const int* __restrict__ dst,
                              int* __restrict__ cursor2, int* __restrict__ csr, int E) {
    const int s  = blockIdx.x & (NXCD - 1);
    const int lo = s * SLICE_N;
    const int hi = lo + SLICE_N;
    const int stride = (gridDim.x >> 3) * blockDim.x;
    for (int i = (blockIdx.x >> 3) * blockDim.x + threadIdx.x; i < E; i += stride) {
        int d = dst[i];
        if (d >= lo && d < hi) {
            int sv = src[i];
            int g = sv / RNG;
            int p = atomicAdd(&cursor2[d * NG + g], 1);
            csr[p] = sv;
        }
    }
}

// ===========================================================================
// K4: XCD-sliced gather with 8 interleaved node-chains per wave.
// Slice (g,h) footprint = 25000 rows x 128B = 3.2MB -> L2-resident.
// Lanes = (edge parity r, 32 channels). Per while-trip: 8 independent
// csr->x load chains in flight (dead chains load csr[0]/row hot lines).
// ===========================================================================
__global__ void __launch_bounds__(256)
gatherP_kernel(const float* __restrict__ x, const int* __restrict__ off2,
               const int* __restrict__ csr,
               float* __restrict__ P0, float* __restrict__ P1,
               float* __restrict__ P2, float* __restrict__ P3) {
    const int sid = blockIdx.x & (NXCD - 1);
    const int g = sid >> 1;
    const int h = sid & 1;
    float* __restrict__ P = (g == 0) ? P0 : (g == 1) ? P1 : (g == 2) ? P2 : P3;
    const int chunk = blockIdx.x >> 3;          // < GCH
    const int n0 = chunk * NPC;
    const int wid  = threadIdx.x >> 6;
    const int lane = threadIdx.x & 63;
    const int r  = lane >> 5;                   // edge parity
    const int cc = lane & 31;                   // channel within half
    const float* __restrict__ xs = x + h * 32 + cc;

    for (int n = n0 + 8 * wid; n < n0 + NPC; n += 32) {
        int j[8], e[8];
        float s[8];
#pragma unroll
        for (int i = 0; i < 8; ++i) {
            j[i] = off2[4 * (n + i) + g] + r;
            e[i] = off2[4 * (n + i) + g + 1];
            s[i] = 0.0f;
        }

        while (true) {
            bool p[8];
            bool any = false;
#pragma unroll
            for (int i = 0; i < 8; ++i) { p[i] = j[i] < e[i]; any = any || p[i]; }
            if (!any) break;

            float t[8];
#pragma unroll
            for (int i = 0; i < 8; ++i) {
                int q = csr[p[i] ? j[i] : 0];   // dead chains hit hot line
                t[i] = xs[(size_t)q * C];
            }
#pragma unroll
            for (int i = 0; i < 8; ++i) {
                s[i] += p[i] ? t[i] : 0.0f;
                j[i] += 2;
            }
        }

#pragma unroll
        for (int i = 0; i < 8; ++i)
            s[i] += __shfl_xor(s[i], 32);
        if (r == 0) {
#pragma unroll
            for (int i = 0; i < 8; ++i)
                __builtin_nontemporal_store(s[i], &P[(size_t)(n + i) * C + h * 32 + cc]);
        }
    }
}

// ===========================================================================
// K5: GEMM [mean|x](100K x 128) @ [Wl;Wr]^T via mfma_f32_16x16x32_bf16.
// Per wave: 16-node tile, 4 col-blocks x 4 k-steps = 16 MFMAs.
// Fused bias+relu+L2norm epilogue. P3 = d_out read-before-write (tile-local).
// ===========================================================================
__global__ void __launch_bounds__(256)
transform_mfma_kernel(const float* __restrict__ x, const int* __restrict__ off2,
                      const float* __restrict__ P0, const float* __restrict__ P1,
                      const float* __restrict__ P2, const float* __restrict__ P3,
                      const float* __restrict__ Wl, const float* __restrict__ bl,
                      const float* __restrict__ Wr, float* __restrict__ out) {
    const int lane = threadIdx.x & 63;
    const int wid  = threadIdx.x >> 6;
    const int col  = lane & 15;
    const int lg   = lane >> 4;

    bf16x8 Bf[4][4];
    float bias[4];
#pragma unroll
    for (int cb = 0; cb < 4; ++cb) {
        const int cc = cb * 16 + col;
        bias[cb] = bl[cc];
#pragma unroll
        for (int ks = 0; ks < 4; ++ks) {
            const int kk0 = ks * 32 + lg * 8;
            const float* W = (kk0 < 64) ? (Wl + (size_t)cc * 64 + kk0)
                                        : (Wr + (size_t)cc * 64 + (kk0 - 64));
            float4 w0 = *(const float4*)W;
            float4 w1 = *(const float4*)(W + 4);
            bf16x8 b;
            b[0]=(short)f2bf(w0.x); b[1]=(short)f2bf(w0.y);
            b[2]=(short)f2bf(w0.z); b[3]=(short)f2bf(w0.w);
            b[4]=(short)f2bf(w1.x); b[5]=(short)f2bf(w1.y);
            b[6]=(short)f2bf(w1.z); b[7]=(short)f2bf(w1.w);
            Bf[cb][ks] = b;
        }
    }

    const int ntiles = N_NODES / 16;
    for (int t = blockIdx.x * 4 + wid; t < ntiles; t += gridDim.x * 4) {
        const int n0 = t * 16;
        const int arow = n0 + col;
        const int d0 = off2[4 * arow];
        const int d1 = off2[4 * arow + 4];
        const int deg = d1 - d0;
        const float inv = 1.0f / (float)(deg > 1 ? deg : 1);

        f32x4 acc[4];
#pragma unroll
        for (int cb = 0; cb < 4; ++cb) acc[cb] = f32x4{0.f, 0.f, 0.f, 0.f};

#pragma unroll
        for (int ks = 0; ks < 4; ++ks) {
            const int kk0 = ks * 32 + lg * 8;
            bf16x8 a;
            if (kk0 < 64) {
                const float4* p0 = (const float4*)(P0 + (size_t)arow * C + kk0);
                const float4* p1 = (const float4*)(P1 + (size_t)arow * C + kk0);
                const float4* p2 = (const float4*)(P2 + (size_t)arow * C + kk0);
                const float4* p3 = (const float4*)(P3 + (size_t)arow * C + kk0);
                float4 a0 = p0[0], b0 = p1[0], c0 = p2[0], e0 = p3[0];
                float4 a1 = p0[1], b1 = p1[1], c1 = p2[1], e1 = p3[1];
                float s0x = ((a0.x + b0.x) + (c0.x + e0.x)) * inv;
                float s0y = ((a0.y + b0.y) + (c0.y + e0.y)) * inv;
                float s0z = ((a0.z + b0.z) + (c0.z + e0.z)) * inv;
                float s0w = ((a0.w + b0.w) + (c0.w + e0.w)) * inv;
                float s1x = ((a1.x + b1.x) + (c1.x + e1.x)) * inv;
                float s1y = ((a1.y + b1.y) + (c1.y + e1.y)) * inv;
                float s1z = ((a1.z + b1.z) + (c1.z + e1.z)) * inv;
                float s1w = ((a1.w + b1.w) + (c1.w + e1.w)) * inv;
                a[0]=(short)f2bf(s0x); a[1]=(short)f2bf(s0y);
                a[2]=(short)f2bf(s0z); a[3]=(short)f2bf(s0w);
                a[4]=(short)f2bf(s1x); a[5]=(short)f2bf(s1y);
                a[6]=(short)f2bf(s1z); a[7]=(short)f2bf(s1w);
            } else {
                const float4* xp = (const float4*)(x + (size_t)arow * C + (kk0 - 64));
                float4 v0 = xp[0], v1 = xp[1];
                a[0]=(short)f2bf(v0.x); a[1]=(short)f2bf(v0.y);
                a[2]=(short)f2bf(v0.z); a[3]=(short)f2bf(v0.w);
                a[4]=(short)f2bf(v1.x); a[5]=(short)f2bf(v1.y);
                a[6]=(short)f2bf(v1.z); a[7]=(short)f2bf(v1.w);
            }
#pragma unroll
            for (int cb = 0; cb < 4; ++cb)
                acc[cb] = __builtin_amdgcn_mfma_f32_16x16x32_bf16(a, Bf[cb][ks], acc[cb], 0, 0, 0);
        }

#pragma unroll
        for (int jj = 0; jj < 4; ++jj) {
            float v0 = fmaxf(acc[0][jj] + bias[0], 0.0f);
            float v1 = fmaxf(acc[1][jj] + bias[1], 0.0f);
            float v2 = fmaxf(acc[2][jj] + bias[2], 0.0f);
            float v3 = fmaxf(acc[3][jj] + bias[3], 0.0f);
            float sS = (v0 * v0 + v1 * v1) + (v2 * v2 + v3 * v3);
            sS += __shfl_xor(sS, 1);
            sS += __shfl_xor(sS, 2);
            sS += __shfl_xor(sS, 4);
            sS += __shfl_xor(sS, 8);
            float rr = 1.0f / (sqrtf(sS) + EPS);
            const int n = n0 + lg * 4 + jj;
            float* o = out + (size_t)n * C + col;
            o[0]  = v0 * rr;
            o[16] = v1 * rr;
            o[32] = v2 * rr;
            o[48] = v3 * rr;
        }
    }
}

// ===========================================================================
extern "C" void kernel_launch(void* const* d_in, const int* in_sizes, int n_in,
                              void* d_out, int out_size, void* d_ws, size_t ws_size,
                              hipStream_t stream) {
    const float* x    = (const float*)d_in[0];
    const int*   edge = (const int*)d_in[1];
    const float* Wl   = (const float*)d_in[2];
    const float* bl   = (const float*)d_in[3];
    const float* Wr   = (const float*)d_in[4];

    const int E = in_sizes[1] / 2;
    const int* src = edge;
    const int* dst = edge + E;
    const int Epad = (E + 3) & ~3;
    const int bcap = E / NXCD + 32768;

    const size_t nc = (size_t)N_NODES * C;

    // layout: P0 P1 P2 | cnt2 bcur cursor2 off2 bsum csr | bsrc bkey16
    float* P0   = (float*)d_ws;
    float* P1   = P0 + nc;
    float* P2   = P1 + nc;
    int* cnt2    = (int*)(P2 + nc);
    int* bcur    = cnt2 + KEYS;
    int* cursor2 = bcur + 8;
    int* off2    = cursor2 + KEYS;         // KEYS+4 reserved
    int* bsum    = off2 + KEYS + 4;        // 512
    int* csr     = bsum + 512;             // Epad
    int* bsrc    = csr + Epad;             // 8*bcap
    u16* bkey16  = (u16*)(bsrc + (size_t)8 * bcap);
    float* P3    = (float*)d_out;

    const size_t baseInts = 3ull * KEYS + 12 + 4 + 512 + Epad;
    const size_t needB = 3ull * nc * 4 + baseInts * 4;
    const size_t needA = needB + (size_t)8 * bcap * 6;

    // zero cnt2 + bcur (adjacent)
    hipMemsetAsync(cnt2, 0, (size_t)(KEYS + 8) * sizeof(int), stream);

    if (ws_size >= needA) {
        partition_kernel<<<1024, 256, 0, stream>>>(src, dst, bcur, bkey16, bsrc, E, bcap);
        hist2p_kernel<<<NXCD * 96, 256, 0, stream>>>(bcur, bkey16, cnt2, bcap);
        scan_block_kernel<<<NBLK2, SCAN_BLK, 0, stream>>>(cnt2, off2, bsum, KEYS);
        scan_bsum_kernel<<<1, 512, 0, stream>>>(bsum, NBLK2);
        scan_add_kernel<<<NBLK2, SCAN_BLK, 0, stream>>>(off2, bsum, cursor2, KEYS, E);
        build2p_kernel<<<NXCD * 96, 256, 0, stream>>>(bcur, bkey16, bsrc, cursor2, csr, bcap);
    } else {
        hist2_kernel<<<NXCD * 256, 256, 0, stream>>>(src, dst, cnt2, E);
        scan_block_kernel<<<NBLK2, SCAN_BLK, 0, stream>>>(cnt2, off2, bsum, KEYS);
        scan_bsum_kernel<<<1, 512, 0, stream>>>(bsum, NBLK2);
        scan_add_kernel<<<NBLK2, SCAN_BLK, 0, stream>>>(off2, bsum, cursor2, KEYS, E);
        build2_kernel<<<NXCD * 256, 256, 0, stream>>>(src, dst, cursor2, csr, E);
    }
    gatherP_kernel<<<NXCD * GCH, 256, 0, stream>>>(x, off2, csr, P0, P1, P2, P3);
    transform_mfma_kernel<<<1024, 256, 0, stream>>>(x, off2, P0, P1, P2, P3,
                                                    Wl, bl, Wr, (float*)d_out);
}